// Round 5
// baseline (249.050 us; speedup 1.0000x reference)
//
#include <hip/hip_runtime.h>
#include <hip/hip_bf16.h>

// GlobalAttn: x = lrelu(concat(q,k) @ w1^T + b1); attn[e,h] = x[e,h,:]·w2[h,:];
// out = segment_softmax(attn, index). E=320000, D=256, K=512, H=4, N=10000.
//
// m201-style 8-phase GEMM: BM=256, BN=256 (full N), BK=64, 8 K-steps
// (= 8 groups x 4 phases), 8 waves as 2M x 4N (128x64 per wave, acc[8][4]).
// LDS 128 KB dynamic: A,B [256][64] bf16 double-buffered, XOR-swizzled
// (byte ^= (row&7)<<4). B staged via global_load_lds (linear dest +
// inverse-swizzled source, rule #21); A (fp32 q|k) reg-staged: 2 float4
// loads/phase -> cvt -> 1 swizzled ds_write_b128/phase (T14 split).
// Counted waits (per-thread vmem FIFO, derived):
//   entering group g: outstanding = a(g+1) x8
//   p0: +B(g+1) x4 -> vmcnt(10) retires a-pair0; each phase vmcnt(10);
//   p3 extra vmcnt(8) = B(g+1) landed. Never drains to 0 (T4).
// Groups 6,7 stage dummy (modular) steps to keep counts uniform; dummy
// ops are newer in the FIFO so waits only become more conservative.

typedef __attribute__((ext_vector_type(8))) short bf16x8;
typedef __attribute__((ext_vector_type(4))) float f32x4;
typedef __attribute__((ext_vector_type(4))) short s16x4;

#define NNODES 10000

__device__ __forceinline__ short f2bf(float f) {
    __hip_bfloat16 h = __float2bfloat16(f);   // RNE
    return *reinterpret_cast<short*>(&h);
}

__device__ __forceinline__ void gload_lds16(const void* g, void* l) {
    __builtin_amdgcn_global_load_lds(
        (const __attribute__((address_space(1))) unsigned int*)g,
        (__attribute__((address_space(3))) unsigned int*)l, 16, 0, 0);
}

// ---- w1 fp32 [256][512] -> bf16 (once per call) ----
__global__ void w1_cvt(const float* __restrict__ w1, short* __restrict__ w1b) {
    int i = (blockIdx.x * 256 + threadIdx.x) * 4;
    float4 v = *(const float4*)(w1 + i);
    s16x4 o; o[0] = f2bf(v.x); o[1] = f2bf(v.y); o[2] = f2bf(v.z); o[3] = f2bf(v.w);
    *(s16x4*)(w1b + i) = o;
}

__global__ void seg_init(float* __restrict__ segsum, int n) {
    int i = blockIdx.x * blockDim.x + threadIdx.x;
    if (i < n) segsum[i] = 0.f;
}

// ---------------- main fused GEMM + epilogue ----------------
__global__ __launch_bounds__(512, 2) void attn_gemm(
    const float* __restrict__ q, const float* __restrict__ kk_,
    const short* __restrict__ w1b, const float* __restrict__ b1,
    const float* __restrict__ w2, const int* __restrict__ index,
    float* __restrict__ attn, float* __restrict__ segsum)
{
    extern __shared__ __align__(16) short smem[];  // [2 bufs][A 16384 | B 16384] shorts

    const int tid  = threadIdx.x;
    const int lane = tid & 63;
    const int w    = tid >> 6;
    const int wm   = w >> 2;          // 0..1 (M)
    const int wn   = w & 3;           // 0..3 (N == head)
    const int l15  = lane & 15;
    const int lhi  = lane >> 4;
    const int row0 = blockIdx.x * 256;   // 1250 blocks

    const int arow = tid >> 3;        // 0..63: row within a 64-row chunk
    const int asub = tid & 7;         // 8-elem k-chunk index
    const int xsub = asub ^ (arow & 7);             // swizzled chunk slot
    const int aw0  = arow * 128 + xsub * 16;        // A ds_write base byte

    f32x4 acc[8][4];
#pragma unroll
    for (int i = 0; i < 8; ++i)
#pragma unroll
        for (int j = 0; j < 4; ++j) acc[i][j] = (f32x4){0.f, 0.f, 0.f, 0.f};

    float4 ar0[4], ar1[4];   // staging regs, chunk-indexed (static via unroll)

    // ---- prologue: load a(0); issue B(0); write A(0); load a(1) ----
    {
#pragma unroll
        for (int c = 0; c < 4; ++c) {
            const float* p = q + (size_t)(row0 + c * 64 + arow) * 256 + asub * 8;
            ar0[c] = *(const float4*)p; ar1[c] = *(const float4*)(p + 4);
        }
        char* bb = (char*)(smem + 32768);
#pragma unroll
        for (int i2 = 0; i2 < 4; ++i2)
            gload_lds16(w1b + i2 * 32768 + arow * 512 + xsub * 8,
                        bb + (i2 * 512 + tid) * 16);
        asm volatile("s_waitcnt vmcnt(4)" ::: "memory");   // a(0) done, B(0) flying
        __builtin_amdgcn_sched_barrier(0);
        char* dA = (char*)smem;
#pragma unroll
        for (int c = 0; c < 4; ++c) {
            bf16x8 pk;
            pk[0] = f2bf(ar0[c].x); pk[1] = f2bf(ar0[c].y);
            pk[2] = f2bf(ar0[c].z); pk[3] = f2bf(ar0[c].w);
            pk[4] = f2bf(ar1[c].x); pk[5] = f2bf(ar1[c].y);
            pk[6] = f2bf(ar1[c].z); pk[7] = f2bf(ar1[c].w);
            *(bf16x8*)(dA + c * 8192 + aw0) = pk;
            // load a(1): step 1 -> q, k-offset 64 floats
            const float* p = q + (size_t)(row0 + c * 64 + arow) * 256 + 64 + asub * 8;
            ar0[c] = *(const float4*)p; ar1[c] = *(const float4*)(p + 4);
        }
        asm volatile("s_waitcnt vmcnt(8)" ::: "memory");   // B(0) landed, a(1) flying
        __builtin_amdgcn_sched_barrier(0);
        asm volatile("s_waitcnt lgkmcnt(0)" ::: "memory");
        __builtin_amdgcn_s_barrier();
    }

    // ---- 8 groups x 4 phases ----
    bf16x8 bfr[4];
#pragma unroll 2
    for (int g = 0; g < 8; ++g) {
        const int cur = g & 1, nxt = cur ^ 1;
        const int SM1 = (g + 1) & 7;                 // staged B step (mod: dummy at g=7)
        const int SM2 = (g + 2) & 7;                 // loaded A step (dummy g>=6)
        const int koB = SM1 * 64;                    // shorts
        const float* a2b = (SM2 < 4) ? q : kk_;
        const int koA = (SM2 & 3) * 64;              // floats
        const char* sA = (const char*)(smem + cur * 16384);
        const char* sB = (const char*)(smem + 32768 + cur * 16384);
        char* dA = (char*)(smem + nxt * 16384);
        char* dB = (char*)(smem + 32768 + nxt * 16384);
#pragma unroll
        for (int p = 0; p < 4; ++p) {
            const int kk = p >> 1;                   // k-half of this step
            const int fb = (p & 1) * 4;              // fm block 0..3 / 4..7
            if ((p & 1) == 0) {                      // (re)load B frags for kk
#pragma unroll
                for (int fn = 0; fn < 4; ++fn) {
                    const int d = wn * 64 + fn * 16 + l15;
                    bfr[fn] = *(const bf16x8*)(sB + d * 128 +
                               ((kk * 64 + lhi * 16) ^ ((d & 7) << 4)));
                }
            }
            bf16x8 afr[4];
#pragma unroll
            for (int i2 = 0; i2 < 4; ++i2) {
                const int r = wm * 128 + (fb + i2) * 16 + l15;
                afr[i2] = *(const bf16x8*)(sA + r * 128 +
                           ((kk * 64 + lhi * 16) ^ ((r & 7) << 4)));
            }
            if (p == 0) {                            // issue 4 B gloads for step g+1
#pragma unroll
                for (int i2 = 0; i2 < 4; ++i2)
                    gload_lds16(w1b + i2 * 32768 + arow * 512 + xsub * 8 + koB,
                                dB + (i2 * 512 + tid) * 16);
            }
            asm volatile("s_waitcnt vmcnt(10)" ::: "memory");  // a(g+1) chunk p ready
            __builtin_amdgcn_sched_barrier(0);
            {   // write A(g+1) chunk p; then refill regs with a(g+2) chunk p
                bf16x8 pk;
                pk[0] = f2bf(ar0[p].x); pk[1] = f2bf(ar0[p].y);
                pk[2] = f2bf(ar0[p].z); pk[3] = f2bf(ar0[p].w);
                pk[4] = f2bf(ar1[p].x); pk[5] = f2bf(ar1[p].y);
                pk[6] = f2bf(ar1[p].z); pk[7] = f2bf(ar1[p].w);
                *(bf16x8*)(dA + p * 8192 + aw0) = pk;
                const float* pp = a2b + (size_t)(row0 + p * 64 + arow) * 256 + koA + asub * 8;
                ar0[p] = *(const float4*)pp; ar1[p] = *(const float4*)(pp + 4);
            }
            if (p == 3) {
                asm volatile("s_waitcnt vmcnt(8)" ::: "memory");  // B(g+1) landed
                __builtin_amdgcn_sched_barrier(0);
            }
            __builtin_amdgcn_s_barrier();
            asm volatile("s_waitcnt lgkmcnt(0)" ::: "memory");
            __builtin_amdgcn_sched_barrier(0);
            __builtin_amdgcn_s_setprio(1);
#pragma unroll
            for (int i2 = 0; i2 < 4; ++i2)
#pragma unroll
                for (int fn = 0; fn < 4; ++fn)
                    acc[fb + i2][fn] = __builtin_amdgcn_mfma_f32_16x16x32_bf16(
                        afr[i2], bfr[fn], acc[fb + i2][fn], 0, 0, 0);
            __builtin_amdgcn_s_setprio(0);
            __builtin_amdgcn_s_barrier();
        }
    }

    // ---- epilogue: bias + lrelu + dot(w2) + exp + atomicAdd(segsum) ----
    float bias[4], w2v[4];
#pragma unroll
    for (int fn = 0; fn < 4; ++fn) {
        int col = wn * 64 + fn * 16 + l15;
        bias[fn] = b1[col];
        w2v[fn]  = w2[col];
    }
#pragma unroll
    for (int fm = 0; fm < 8; ++fm) {
#pragma unroll
        for (int r = 0; r < 4; ++r) {
            int row = row0 + wm * 128 + fm * 16 + lhi * 4 + r;  // C/D: row=(l>>4)*4+reg
            float p = 0.f;
#pragma unroll
            for (int fn = 0; fn < 4; ++fn) {
                float y = acc[fm][fn][r] + bias[fn];
                y = (y > 0.f) ? y : 0.01f * y;
                p += y * w2v[fn];
            }
#pragma unroll
            for (int m = 1; m < 16; m <<= 1) p += __shfl_xor(p, m);
            if (l15 == 0) {
                float e = __expf(p);
                attn[(size_t)row * 4 + wn] = e;
                atomicAdd(&segsum[index[row] * 4 + wn], e);
            }
        }
    }
}

__global__ void seg_norm(const float* __restrict__ attn, const int* __restrict__ index,
                         const float* __restrict__ segsum, float* __restrict__ out, int total) {
    int i = blockIdx.x * blockDim.x + threadIdx.x;
    if (i >= total) return;
    int e = i >> 2, h = i & 3;
    out[i] = attn[i] / (segsum[index[e] * 4 + h] + 1e-16f);
}

extern "C" void kernel_launch(void* const* d_in, const int* in_sizes, int n_in,
                              void* d_out, int out_size, void* d_ws, size_t ws_size,
                              hipStream_t stream) {
    const float* q   = (const float*)d_in[0];
    const float* k   = (const float*)d_in[1];
    const float* w1  = (const float*)d_in[2];
    const float* b1  = (const float*)d_in[3];
    const float* w2  = (const float*)d_in[4];
    const int* index = (const int*)d_in[5];

    const int nE = in_sizes[0] / 256;      // 320000
    char* ws = (char*)d_ws;
    float* attn   = (float*)ws;            ws += (size_t)nE * 4 * 4;
    float* segsum = (float*)ws;            ws += (size_t)NNODES * 4 * 4;
    short* w1bf   = (short*)ws;            // 256*512 bf16 = 256KB (dummy reads stay in-bounds)
    float* out    = (float*)d_out;

    hipFuncSetAttribute((const void*)attn_gemm,
                        hipFuncAttributeMaxDynamicSharedMemorySize, 131072);

    w1_cvt<<<128, 256, 0, stream>>>(w1, w1bf);
    seg_init<<<(NNODES * 4 + 255) / 256, 256, 0, stream>>>(segsum, NNODES * 4);

    attn_gemm<<<nE / 256, 512, 131072, stream>>>(q, k, w1bf, b1, w2, index, attn, segsum);

    int total = nE * 4;
    seg_norm<<<(total + 255) / 256, 256, 0, stream>>>(attn, index, segsum, out, total);
}